// Round 1
// baseline (233.967 us; speedup 1.0000x reference)
//
#include <hip/hip_runtime.h>
#include <cstdint>
#include <cstddef>

// ---------------------------------------------------------------------------
// Conv2d 3x3 s1 p1 on 16-bit fixed-point (12 frac bits) quantized operands.
// x: (32,128,56,56) f32   w: (256,128,3,3) f32   out: (32,256,56,56) f32
// Strategy: quantize->bf16, implicit GEMM M=256, N=32*56*56=100352=784*128,
// K=9*128=1152, m97-style 128x128 tile w/ mfma_f32_16x16x32_bf16 and
// global_load_lds width=16 staging.
// ---------------------------------------------------------------------------

typedef __attribute__((ext_vector_type(8))) short short8;
typedef __attribute__((ext_vector_type(4))) float floatx4;

#define NIMG 32
#define CIN  128
#define HW   56
#define KOUT 256
#define HP   58                                   // padded H/W
#define XPAD_ELEMS ((size_t)NIMG * HP * HP * CIN) // 13,778,944
#define WT_OFF_BYTES (XPAD_ELEMS * 2)             // 27,557,888 (256B aligned)
#define KK 1152

__device__ __forceinline__ uint16_t quant_bf16(float v) {
    // round-half-even to 12 frac bits, clip to int16 range, then RNE to bf16
    float q = rintf(v * 4096.0f);
    q = fminf(fmaxf(q, -32768.0f), 32767.0f) * (1.0f / 4096.0f);
    union { float f; uint32_t u; } cv; cv.f = q;
    uint32_t u = cv.u;
    return (uint16_t)((u + 0x7fffu + ((u >> 16) & 1u)) >> 16);
}

// ---- transform x: NCHW f32 -> padded NHWC bf16 [32][58][58][128] ----------
__global__ __launch_bounds__(256) void quant_pad_x(const float* __restrict__ x,
                                                   uint16_t* __restrict__ xp) {
    const int b = blockIdx.x;            // 0..32*56-1, one (n, h) row each
    const int n = b / HW, h = b - n * HW;
    __shared__ uint16_t tile[HW * 130];  // [w][c], +2 pad breaks bank conflicts
    const float* src = x + (size_t)n * CIN * HW * HW + (size_t)h * HW; // + c*3136 + w
    for (int t = threadIdx.x; t < CIN * HW; t += 256) {
        int c = t / HW, w = t - c * HW;  // consecutive t -> consecutive w (coalesced reads)
        tile[w * 130 + c] = quant_bf16(src[(size_t)c * (HW * HW) + w]);
    }
    __syncthreads();
    // interior row (n, h+1, cols 1..56): 56*128 contiguous bf16
    uint32_t* dst = (uint32_t*)(xp + ((size_t)(n * HP + h + 1) * HP + 1) * CIN);
    for (int t = threadIdx.x; t < (HW * CIN) / 2; t += 256) {
        int w = t >> 6;            // pair-index: c2 = t&63 -> channels 2c2, 2c2+1
        int c2 = t & 63;
        uint32_t lo = tile[w * 130 + c2 * 2];
        uint32_t hi = tile[w * 130 + c2 * 2 + 1];
        dst[t] = lo | (hi << 16);
    }
}

// ---- transform w: OIHW f32 -> Wt[k][tap*128+c] bf16 ------------------------
__global__ __launch_bounds__(256) void quant_w(const float* __restrict__ w,
                                               uint16_t* __restrict__ wt) {
    int i = blockIdx.x * 256 + threadIdx.x;   // 256*1152 = 294912 exact
    int k = i / KK;
    int r = i - k * KK;
    int tap = r >> 7;          // 0..8
    int c = r & 127;
    wt[i] = quant_bf16(w[(size_t)(k * CIN + c) * 9 + tap]);
}

// ---- main implicit GEMM ----------------------------------------------------
// grid: (2 kblk, 784 pxblk), 256 threads (4 waves), 128x128 tile, BK=32.
__global__ __launch_bounds__(256) void conv_gemm(const uint16_t* __restrict__ xp,
                                                 const uint16_t* __restrict__ wt,
                                                 float* __restrict__ out) {
    __shared__ __align__(16) uint16_t As[128 * 32]; // [k_out_local][32 kk]  8KB
    __shared__ __align__(16) uint16_t Bs[128 * 32]; // [px_local][32 kk]     8KB

    const int tid = threadIdx.x;
    const int l   = tid & 63;
    const int wv  = tid >> 6;
    const int wr  = wv >> 1;      // wave row (k_out 64-half)
    const int wc  = wv & 1;       // wave col (px 64-half)
    const int kblk  = blockIdx.x; // 0..1
    const int pxblk = blockIdx.y; // 0..783

    const int chunk = l & 3;      // 16B chunk within a 64B row
    const int sub   = l >> 2;     // 0..15 row-within-16

    // Per-lane global staging base pointers (fixed across K loop).
    const uint16_t* aG[2];
    const uint16_t* bG[2];
#pragma unroll
    for (int i = 0; i < 2; ++i) {
        int row = wv * 32 + i * 16 + sub;                 // 0..127
        aG[i] = wt + (size_t)(kblk * 128 + row) * KK + chunk * 8;
        int p = pxblk * 128 + row;                        // global pixel id
        int n = p / 3136; int rem = p - n * 3136;
        int hh = rem / HW; int ww = rem - hh * HW;
        // tap (ty,tx in 0..2) reads padded (hh+ty, ww+tx); base at tap (0,0)
        bG[i] = xp + (size_t)((n * HP + hh) * HP + ww) * CIN + chunk * 8;
    }

    floatx4 acc[4][4];
#pragma unroll
    for (int a = 0; a < 4; ++a)
#pragma unroll
        for (int b = 0; b < 4; ++b)
            acc[a][b] = (floatx4){0.f, 0.f, 0.f, 0.f};

    const int m16 = l & 15;
    const int q   = l >> 4;

    for (int tap = 0; tap < 9; ++tap) {
        const int toff = (tap / 3) * HP + (tap % 3);      // uniform scalar
#pragma unroll
        for (int c4 = 0; c4 < 4; ++c4) {
            const int kt = tap * 4 + c4;
            // stage A,B tiles: wave-uniform LDS base + lane*16 (HW semantics)
#pragma unroll
            for (int i = 0; i < 2; ++i) {
                __builtin_amdgcn_global_load_lds(
                    (__attribute__((address_space(1))) void*)(void*)(aG[i] + kt * 32),
                    (__attribute__((address_space(3))) void*)(void*)(&As[wv * 1024 + i * 512]),
                    16, 0, 0);
                __builtin_amdgcn_global_load_lds(
                    (__attribute__((address_space(1))) void*)(void*)(bG[i] + toff * CIN + c4 * 32),
                    (__attribute__((address_space(3))) void*)(void*)(&Bs[wv * 1024 + i * 512]),
                    16, 0, 0);
            }
            __syncthreads();
            short8 af[4], bf[4];
#pragma unroll
            for (int f = 0; f < 4; ++f) {
                af[f] = *(const short8*)&As[(wr * 64 + f * 16 + m16) * 32 + q * 8];
                bf[f] = *(const short8*)&Bs[(wc * 64 + f * 16 + m16) * 32 + q * 8];
            }
#pragma unroll
            for (int fr = 0; fr < 4; ++fr)
#pragma unroll
                for (int fc = 0; fc < 4; ++fc)
                    acc[fr][fc] = __builtin_amdgcn_mfma_f32_16x16x32_bf16(
                        af[fr], bf[fc], acc[fr][fc], 0, 0, 0);
            __syncthreads();
        }
    }

    // Epilogue: D row = k_out (quad*4+reg), col = px (lane&15).
#pragma unroll
    for (int fc = 0; fc < 4; ++fc) {
        int p = pxblk * 128 + wc * 64 + fc * 16 + m16;
        int n = p / 3136; int rem = p - n * 3136;
        float* op = out + (size_t)(n * KOUT + kblk * 128) * 3136 + rem;
#pragma unroll
        for (int fr = 0; fr < 4; ++fr) {
            int kl = wr * 64 + fr * 16 + q * 4;
#pragma unroll
            for (int t = 0; t < 4; ++t)
                op[(size_t)(kl + t) * 3136] = acc[fr][fc][t];
        }
    }
}

extern "C" void kernel_launch(void* const* d_in, const int* in_sizes, int n_in,
                              void* d_out, int out_size, void* d_ws, size_t ws_size,
                              hipStream_t stream) {
    const float* x = (const float*)d_in[0];
    const float* w = (const float*)d_in[1];
    float* out = (float*)d_out;

    uint16_t* xp  = (uint16_t*)d_ws;                           // 27.56 MB padded bf16 x
    uint16_t* wtb = (uint16_t*)((char*)d_ws + WT_OFF_BYTES);   // 0.59 MB bf16 weights

    // zero the padded activation buffer (borders must be 0; ws is poisoned 0xAA)
    hipMemsetAsync(d_ws, 0, WT_OFF_BYTES, stream);
    quant_pad_x<<<NIMG * HW, 256, 0, stream>>>(x, xp);
    quant_w<<<(KOUT * KK) / 256, 256, 0, stream>>>(w, wtb);

    dim3 grid(2, 784);  // kblk fast-varying: adjacent blocks share the B tile (L2)
    conv_gemm<<<grid, 256, 0, stream>>>(xp, wtb, out);
}

// Round 2
// 227.709 us; speedup vs baseline: 1.0275x; 1.0275x over previous
//
#include <hip/hip_runtime.h>
#include <cstdint>
#include <cstddef>

// ---------------------------------------------------------------------------
// Conv2d 3x3 s1 p1 on 16-bit fixed-point (12 frac bits) quantized operands.
// x: (32,128,56,56) f32   w: (256,128,3,3) f32   out: (32,256,56,56) f32
// Implicit GEMM M=256, N=100352, K=1152, 128x128 tile, mfma_f32_16x16x32_bf16,
// global_load_lds width=16 staging with XOR bank swizzle on the chunk index.
// ---------------------------------------------------------------------------

typedef __attribute__((ext_vector_type(8))) short short8;
typedef __attribute__((ext_vector_type(4))) float floatx4;

#define NIMG 32
#define CIN  128
#define HW   56
#define KOUT 256
#define HP   58                                   // padded H/W
#define XPAD_ELEMS ((size_t)NIMG * HP * HP * CIN) // 13,778,944
#define WT_OFF_BYTES (XPAD_ELEMS * 2)             // 27,557,888 (256B aligned)
#define KK 1152

__device__ __forceinline__ uint16_t quant_bf16(float v) {
    // round-half-even to 12 frac bits, clip to int16 range, then RNE to bf16
    float q = rintf(v * 4096.0f);
    q = fminf(fmaxf(q, -32768.0f), 32767.0f) * (1.0f / 4096.0f);
    union { float f; uint32_t u; } cv; cv.f = q;
    uint32_t u = cv.u;
    return (uint16_t)((u + 0x7fffu + ((u >> 16) & 1u)) >> 16);
}

// ---- transform x: NCHW f32 -> padded NHWC bf16 [32][58][58][128] ----------
// Also zeroes the pad border (replaces the 27.5 MB memset dispatch).
__global__ __launch_bounds__(256) void quant_pad_x(const float* __restrict__ x,
                                                   uint16_t* __restrict__ xp) {
    const int b = blockIdx.x;            // one padded row (n, hp) each
    const int n = b / HP, hp = b - n * HP;
    uint16_t* row = xp + (size_t)(n * HP + hp) * HP * CIN;

    if (hp == 0 || hp == HP - 1) {       // top/bottom pad row: all zeros
        uint4 z{0, 0, 0, 0};
        uint4* d = (uint4*)row;
        for (int t = threadIdx.x; t < HP * CIN * 2 / 16; t += 256) d[t] = z;
        return;
    }
    const int h = hp - 1;
    __shared__ uint16_t tile[HW * 130];  // [w][c], +2 pad breaks bank conflicts
    const float* src = x + (size_t)n * CIN * HW * HW + (size_t)h * HW;
    for (int t = threadIdx.x; t < CIN * 14; t += 256) {      // float4 loads
        int c = t / 14, w4 = t - c * 14;
        float4 v = *(const float4*)(src + (size_t)c * (HW * HW) + w4 * 4);
        int base = (w4 * 4) * 130 + c;
        tile[base]       = quant_bf16(v.x);
        tile[base + 130] = quant_bf16(v.y);
        tile[base + 260] = quant_bf16(v.z);
        tile[base + 390] = quant_bf16(v.w);
    }
    __syncthreads();
    if (threadIdx.x < 32) {              // zero left/right pad pixels
        uint4 z{0, 0, 0, 0};
        if (threadIdx.x < 16) ((uint4*)row)[threadIdx.x] = z;
        else ((uint4*)(row + 57 * CIN))[threadIdx.x - 16] = z;
    }
    uint2* dst = (uint2*)(row + CIN);    // interior cols 1..56, 8B stores
    for (int t = threadIdx.x; t < (HW * CIN) / 4; t += 256) {
        int w = t >> 5, c4 = (t & 31) * 4;
        uint32_t a = tile[w * 130 + c4]     | ((uint32_t)tile[w * 130 + c4 + 1] << 16);
        uint32_t c = tile[w * 130 + c4 + 2] | ((uint32_t)tile[w * 130 + c4 + 3] << 16);
        dst[t] = make_uint2(a, c);
    }
}

// ---- transform w: OIHW f32 -> Wt[k][tap*128+c] bf16 ------------------------
__global__ __launch_bounds__(256) void quant_w(const float* __restrict__ w,
                                               uint16_t* __restrict__ wt) {
    int i = blockIdx.x * 256 + threadIdx.x;   // 256*1152 = 294912 exact
    int k = i / KK;
    int r = i - k * KK;
    int tap = r >> 7;          // 0..8
    int c = r & 127;
    wt[i] = quant_bf16(w[(size_t)(k * CIN + c) * 9 + tap]);
}

// ---- main implicit GEMM ----------------------------------------------------
// grid: (2 kblk, 784 pxblk), 256 threads (4 waves), 128x128 tile, BK=32.
// LDS row = 64B = 4 chunks of 16B. Chunk slot s at row r holds data chunk
// s ^ ((r>>2)&3)  (XOR swizzle -> fragment reads are 2-way/free on banks).
__global__ __launch_bounds__(256) void conv_gemm(const uint16_t* __restrict__ xp,
                                                 const uint16_t* __restrict__ wt,
                                                 float* __restrict__ out) {
    __shared__ __align__(16) uint16_t As[128 * 32]; // [k_out_local][32 kk]  8KB
    __shared__ __align__(16) uint16_t Bs[128 * 32]; // [px_local][32 kk]     8KB

    const int tid = threadIdx.x;
    const int l   = tid & 63;
    const int wv  = tid >> 6;
    const int wr  = wv >> 1;      // wave row (k_out 64-half)
    const int wc  = wv & 1;       // wave col (px 64-half)
    const int kblk  = blockIdx.x; // 0..1
    const int pxblk = blockIdx.y; // 0..783

    const int sub    = l >> 2;                      // 0..15 row-within-16
    const int c_data = (l & 3) ^ ((l >> 4) & 3);    // swizzled source chunk

    // Per-lane global staging base pointers (fixed across K loop).
    const uint16_t* aG[2];
    const uint16_t* bG[2];
#pragma unroll
    for (int i = 0; i < 2; ++i) {
        int row = wv * 32 + i * 16 + sub;                 // 0..127
        aG[i] = wt + (size_t)(kblk * 128 + row) * KK + c_data * 8;
        int p = pxblk * 128 + row;                        // global pixel id
        int n = p / 3136; int rem = p - n * 3136;
        int hh = rem / HW; int ww = rem - hh * HW;
        bG[i] = xp + (size_t)((n * HP + hh) * HP + ww) * CIN + c_data * 8;
    }

    floatx4 acc[4][4];
#pragma unroll
    for (int a = 0; a < 4; ++a)
#pragma unroll
        for (int b = 0; b < 4; ++b)
            acc[a][b] = (floatx4){0.f, 0.f, 0.f, 0.f};

    const int m16  = l & 15;
    const int q    = l >> 4;
    const int slot = (q ^ ((m16 >> 2) & 3)) * 8;    // read-side swizzled slot

    for (int tap = 0; tap < 9; ++tap) {
        const int toff = (tap / 3) * HP + (tap % 3);      // uniform scalar
#pragma unroll
        for (int c4 = 0; c4 < 4; ++c4) {
            const int kt = tap * 4 + c4;
#pragma unroll
            for (int i = 0; i < 2; ++i) {
                __builtin_amdgcn_global_load_lds(
                    (__attribute__((address_space(1))) void*)(void*)(aG[i] + kt * 32),
                    (__attribute__((address_space(3))) void*)(void*)(&As[wv * 1024 + i * 512]),
                    16, 0, 0);
                __builtin_amdgcn_global_load_lds(
                    (__attribute__((address_space(1))) void*)(void*)(bG[i] + toff * CIN + c4 * 32),
                    (__attribute__((address_space(3))) void*)(void*)(&Bs[wv * 1024 + i * 512]),
                    16, 0, 0);
            }
            __syncthreads();
            short8 af[4], bf[4];
#pragma unroll
            for (int f = 0; f < 4; ++f) {
                af[f] = *(const short8*)&As[(wr * 64 + f * 16 + m16) * 32 + slot];
                bf[f] = *(const short8*)&Bs[(wc * 64 + f * 16 + m16) * 32 + slot];
            }
#pragma unroll
            for (int fr = 0; fr < 4; ++fr)
#pragma unroll
                for (int fc = 0; fc < 4; ++fc)
                    acc[fr][fc] = __builtin_amdgcn_mfma_f32_16x16x32_bf16(
                        af[fr], bf[fc], acc[fr][fc], 0, 0, 0);
            __syncthreads();
        }
    }

    // Epilogue: D row = k_out (quad*4+reg), col = px (lane&15).
#pragma unroll
    for (int fc = 0; fc < 4; ++fc) {
        int p = pxblk * 128 + wc * 64 + fc * 16 + m16;
        int n = p / 3136; int rem = p - n * 3136;
        float* op = out + (size_t)(n * KOUT + kblk * 128) * 3136 + rem;
#pragma unroll
        for (int fr = 0; fr < 4; ++fr) {
            int kl = wr * 64 + fr * 16 + q * 4;
#pragma unroll
            for (int t = 0; t < 4; ++t)
                op[(size_t)(kl + t) * 3136] = acc[fr][fc][t];
        }
    }
}

extern "C" void kernel_launch(void* const* d_in, const int* in_sizes, int n_in,
                              void* d_out, int out_size, void* d_ws, size_t ws_size,
                              hipStream_t stream) {
    const float* x = (const float*)d_in[0];
    const float* w = (const float*)d_in[1];
    float* out = (float*)d_out;

    uint16_t* xp  = (uint16_t*)d_ws;                           // 27.56 MB padded bf16 x
    uint16_t* wtb = (uint16_t*)((char*)d_ws + WT_OFF_BYTES);   // 0.59 MB bf16 weights

    quant_pad_x<<<NIMG * HP, 256, 0, stream>>>(x, xp);         // covers ALL of xp incl. borders
    quant_w<<<(KOUT * KK) / 256, 256, 0, stream>>>(w, wtb);

    dim3 grid(2, 784);  // kblk fast-varying: adjacent blocks share the B tile (L2)
    conv_gemm<<<grid, 256, 0, stream>>>(xp, wtb, out);
}

// Round 3
// 220.185 us; speedup vs baseline: 1.0626x; 1.0342x over previous
//
#include <hip/hip_runtime.h>
#include <cstdint>
#include <cstddef>

// ---------------------------------------------------------------------------
// Conv2d 3x3 s1 p1 on 16-bit fixed-point (12 frac bits) quantized operands.
// x: (32,128,56,56) f32   w: (256,128,3,3) f32   out: (32,256,56,56) f32
// Implicit GEMM M=256, N=100352, K=1152. 128x128 tile, BK=64 (18 k-steps),
// mfma_f32_16x16x32_bf16, global_load_lds width=16, XOR-8 chunk swizzle.
// ---------------------------------------------------------------------------

typedef __attribute__((ext_vector_type(8))) short short8;
typedef __attribute__((ext_vector_type(4))) float floatx4;

#define NIMG 32
#define CIN  128
#define HW   56
#define KOUT 256
#define HP   58                                   // padded H/W
#define XPAD_ELEMS ((size_t)NIMG * HP * HP * CIN) // 13,778,944
#define WT_OFF_BYTES (XPAD_ELEMS * 2)             // 27,557,888 (256B aligned)
#define KK 1152

__device__ __forceinline__ uint16_t quant_bf16(float v) {
    // round-half-even to 12 frac bits, clip to int16 range, then RNE to bf16
    float q = rintf(v * 4096.0f);
    q = fminf(fmaxf(q, -32768.0f), 32767.0f) * (1.0f / 4096.0f);
    union { float f; uint32_t u; } cv; cv.f = q;
    uint32_t u = cv.u;
    return (uint16_t)((u + 0x7fffu + ((u >> 16) & 1u)) >> 16);
}

// ---- transform x: NCHW f32 -> padded NHWC bf16 [32][58][58][128] ----------
// Also zeroes the pad border (no separate memset dispatch).
__global__ __launch_bounds__(256) void quant_pad_x(const float* __restrict__ x,
                                                   uint16_t* __restrict__ xp) {
    const int b = blockIdx.x;            // one padded row (n, hp) each
    const int n = b / HP, hp = b - n * HP;
    uint16_t* row = xp + (size_t)(n * HP + hp) * HP * CIN;

    if (hp == 0 || hp == HP - 1) {       // top/bottom pad row: all zeros
        uint4 z{0, 0, 0, 0};
        uint4* d = (uint4*)row;
        for (int t = threadIdx.x; t < HP * CIN * 2 / 16; t += 256) d[t] = z;
        return;
    }
    const int h = hp - 1;
    __shared__ uint16_t tile[HW * 130];  // [w][c], +2 pad breaks bank conflicts
    const float* src = x + (size_t)n * CIN * HW * HW + (size_t)h * HW;
    for (int t = threadIdx.x; t < CIN * 14; t += 256) {      // float4 loads
        int c = t / 14, w4 = t - c * 14;
        float4 v = *(const float4*)(src + (size_t)c * (HW * HW) + w4 * 4);
        int base = (w4 * 4) * 130 + c;
        tile[base]       = quant_bf16(v.x);
        tile[base + 130] = quant_bf16(v.y);
        tile[base + 260] = quant_bf16(v.z);
        tile[base + 390] = quant_bf16(v.w);
    }
    __syncthreads();
    if (threadIdx.x < 32) {              // zero left/right pad pixels
        uint4 z{0, 0, 0, 0};
        if (threadIdx.x < 16) ((uint4*)row)[threadIdx.x] = z;
        else ((uint4*)(row + 57 * CIN))[threadIdx.x - 16] = z;
    }
    uint2* dst = (uint2*)(row + CIN);    // interior cols 1..56, 8B stores
    for (int t = threadIdx.x; t < (HW * CIN) / 4; t += 256) {
        int w = t >> 5, c4 = (t & 31) * 4;
        uint32_t a = tile[w * 130 + c4]     | ((uint32_t)tile[w * 130 + c4 + 1] << 16);
        uint32_t c = tile[w * 130 + c4 + 2] | ((uint32_t)tile[w * 130 + c4 + 3] << 16);
        dst[t] = make_uint2(a, c);
    }
}

// ---- transform w: OIHW f32 -> Wt[k][tap*128+c] bf16 ------------------------
__global__ __launch_bounds__(256) void quant_w(const float* __restrict__ w,
                                               uint16_t* __restrict__ wt) {
    int i = blockIdx.x * 256 + threadIdx.x;   // 256*1152 = 294912 exact
    int k = i / KK;
    int r = i - k * KK;
    int tap = r >> 7;          // 0..8
    int c = r & 127;
    wt[i] = quant_bf16(w[(size_t)(k * CIN + c) * 9 + tap]);
}

// ---- main implicit GEMM ----------------------------------------------------
// grid: (2 kblk, 784 pxblk), 256 threads (4 waves), 128x128 tile, BK=64.
// LDS row = 128B = 8 chunks of 16B. Slot s at row r holds data chunk s^(r&7)
// -> fragment reads span all 32 banks at 2-way (free).
// global_load_lds instr i covers 8 rows: lane l -> row (l>>3), slot (l&7),
// so the lane's GLOBAL source chunk is (l&7)^((l>>3)&7).
__global__ __launch_bounds__(256) void conv_gemm(const uint16_t* __restrict__ xp,
                                                 const uint16_t* __restrict__ wt,
                                                 float* __restrict__ out) {
    __shared__ __align__(16) uint16_t As[128 * 64]; // [k_out_local][64 kk] 16KB
    __shared__ __align__(16) uint16_t Bs[128 * 64]; // [px_local][64 kk]    16KB

    const int tid = threadIdx.x;
    const int l   = tid & 63;
    const int wv  = tid >> 6;
    const int wr  = wv >> 1;      // wave row (k_out 64-half)
    const int wc  = wv & 1;       // wave col (px 64-half)
    const int kblk  = blockIdx.x; // 0..1
    const int pxblk = blockIdx.y; // 0..783

    const int srow   = l >> 3;                      // 0..7 row-within-8
    const int c_data = (l & 7) ^ srow;              // swizzled source chunk

    // Per-lane global staging base pointers (fixed across K loop).
    const uint16_t* aG[4];
    const uint16_t* bG[4];
#pragma unroll
    for (int i = 0; i < 4; ++i) {
        int row = wv * 32 + i * 8 + srow;                 // 0..127
        aG[i] = wt + (size_t)(kblk * 128 + row) * KK + c_data * 8;
        int p = pxblk * 128 + row;                        // global pixel id
        int n = p / 3136; int rem = p - n * 3136;
        int hh = rem / HW; int ww = rem - hh * HW;
        bG[i] = xp + (size_t)((n * HP + hh) * HP + ww) * CIN + c_data * 8;
    }

    floatx4 acc[4][4];
#pragma unroll
    for (int a = 0; a < 4; ++a)
#pragma unroll
        for (int b = 0; b < 4; ++b)
            acc[a][b] = (floatx4){0.f, 0.f, 0.f, 0.f};

    const int m16 = l & 15;
    const int q   = l >> 4;
    const int r7  = m16 & 7;      // row&7 for read-side swizzle

    for (int tap = 0; tap < 9; ++tap) {
        const int toff = ((tap / 3) * HP + (tap % 3)) * CIN;  // uniform scalar
#pragma unroll
        for (int c64 = 0; c64 < 2; ++c64) {
            const int koff = tap * 128 + c64 * 64;            // A source kk offset
#pragma unroll
            for (int i = 0; i < 4; ++i) {
                __builtin_amdgcn_global_load_lds(
                    (__attribute__((address_space(1))) void*)(void*)(aG[i] + koff),
                    (__attribute__((address_space(3))) void*)(void*)(&As[(wv * 32 + i * 8) * 64]),
                    16, 0, 0);
                __builtin_amdgcn_global_load_lds(
                    (__attribute__((address_space(1))) void*)(void*)(bG[i] + toff + c64 * 64),
                    (__attribute__((address_space(3))) void*)(void*)(&Bs[(wv * 32 + i * 8) * 64]),
                    16, 0, 0);
            }
            __syncthreads();
#pragma unroll
            for (int s = 0; s < 2; ++s) {       // two k=32 halves of BK=64
                const int slot = ((s * 4 + q) ^ r7) * 8;
                short8 af[4], bf[4];
#pragma unroll
                for (int f = 0; f < 4; ++f) {
                    af[f] = *(const short8*)&As[(wr * 64 + f * 16 + m16) * 64 + slot];
                    bf[f] = *(const short8*)&Bs[(wc * 64 + f * 16 + m16) * 64 + slot];
                }
#pragma unroll
                for (int fr = 0; fr < 4; ++fr)
#pragma unroll
                    for (int fc = 0; fc < 4; ++fc)
                        acc[fr][fc] = __builtin_amdgcn_mfma_f32_16x16x32_bf16(
                            af[fr], bf[fc], acc[fr][fc], 0, 0, 0);
            }
            __syncthreads();
        }
    }

    // Epilogue: D row = k_out (quad*4+reg), col = px (lane&15).
#pragma unroll
    for (int fc = 0; fc < 4; ++fc) {
        int p = pxblk * 128 + wc * 64 + fc * 16 + m16;
        int n = p / 3136; int rem = p - n * 3136;
        float* op = out + (size_t)(n * KOUT + kblk * 128) * 3136 + rem;
#pragma unroll
        for (int fr = 0; fr < 4; ++fr) {
            int kl = wr * 64 + fr * 16 + q * 4;
#pragma unroll
            for (int t = 0; t < 4; ++t)
                op[(size_t)(kl + t) * 3136] = acc[fr][fc][t];
        }
    }
}

extern "C" void kernel_launch(void* const* d_in, const int* in_sizes, int n_in,
                              void* d_out, int out_size, void* d_ws, size_t ws_size,
                              hipStream_t stream) {
    const float* x = (const float*)d_in[0];
    const float* w = (const float*)d_in[1];
    float* out = (float*)d_out;

    uint16_t* xp  = (uint16_t*)d_ws;                           // 27.56 MB padded bf16 x
    uint16_t* wtb = (uint16_t*)((char*)d_ws + WT_OFF_BYTES);   // 0.59 MB bf16 weights

    quant_pad_x<<<NIMG * HP, 256, 0, stream>>>(x, xp);         // covers ALL of xp incl. borders
    quant_w<<<(KOUT * KK) / 256, 256, 0, stream>>>(w, wtb);

    dim3 grid(2, 784);  // kblk fast-varying: adjacent blocks share the B tile (L2)
    conv_gemm<<<grid, 256, 0, stream>>>(xp, wtb, out);
}